// Round 1
// baseline (428.689 us; speedup 1.0000x reference)
//
#include <hip/hip_runtime.h>
#include <math.h>

#define N_NODES 50000
#define N_EDGES 800000

// ---------------- utility ----------------
__global__ void zero_int_kernel(int* __restrict__ p, int n) {
    int i = blockIdx.x * blockDim.x + threadIdx.x;
    if (i < n) p[i] = 0;
}

// counts[dst] += 1 for every edge (self-loops added analytically later)
__global__ void count_kernel(const int* __restrict__ ei, int* __restrict__ counts) {
    int i = blockIdx.x * blockDim.x + threadIdx.x;
    if (i < N_EDGES) {
        int dst = ei[N_EDGES + i];
        atomicAdd(&counts[dst], 1);
    }
}

#define SCAN_T 1024
#define SCAN_ITEMS 49  // 1024*49 = 50176 >= 50000

// single-block exclusive scan of counts -> off; also dinv[n] = rsqrt(deg+1)
__global__ void scan_kernel(const int* __restrict__ counts, int* __restrict__ off,
                            float* __restrict__ dinv) {
    __shared__ int sums[SCAN_T];
    int t = threadIdx.x;
    int base = t * SCAN_ITEMS;
    int local[SCAN_ITEMS];
    int run = 0;
#pragma unroll
    for (int i = 0; i < SCAN_ITEMS; i++) {
        int idx = base + i;
        int c = (idx < N_NODES) ? counts[idx] : 0;
        local[i] = run;
        run += c;
    }
    sums[t] = run;
    __syncthreads();
    for (int o = 1; o < SCAN_T; o <<= 1) {
        int v = (t >= o) ? sums[t - o] : 0;
        __syncthreads();
        if (t >= o) sums[t] += v;
        __syncthreads();
    }
    int carry = (t > 0) ? sums[t - 1] : 0;
    for (int i = 0; i < SCAN_ITEMS; i++) {
        int idx = base + i;
        if (idx < N_NODES) {
            off[idx] = carry + local[i];
            dinv[idx] = rsqrtf((float)(counts[idx] + 1));
        }
    }
    if (t == SCAN_T - 1) off[N_NODES] = sums[SCAN_T - 1];
}

// scatter edges into CSR grouped by dst
__global__ void fill_kernel(const int* __restrict__ ei, const int* __restrict__ off,
                            int* __restrict__ cursor, int* __restrict__ csr_src) {
    int i = blockIdx.x * blockDim.x + threadIdx.x;
    if (i < N_EDGES) {
        int src = ei[i];
        int dst = ei[N_EDGES + i];
        int pos = off[dst] + atomicAdd(&cursor[dst], 1);
        csr_src[pos] = src;
    }
}

// ---------------- GEMM: H[N,C_OUT] = X[N,128] @ W[128,C_OUT] ----------------
template <int C_OUT>
__global__ __launch_bounds__(256) void gemm_kernel(const float* __restrict__ X,
                                                   const float* __restrict__ W,
                                                   float* __restrict__ H) {
    constexpr int K = 128;
    constexpr int ROWS = 32;
    constexpr int GPT = 256 / C_OUT;  // column groups per block: 2 (C=128) or 4 (C=64)
    constexpr int RPG = ROWS / GPT;   // rows per thread: 16 or 8
    __shared__ float xs[ROWS][K];     // 16 KB

    int t = threadIdx.x;
    int rowbase = blockIdx.x * ROWS;

    // cooperative load of the 32x128 x-tile (1024 float4, 4 per thread, coalesced)
#pragma unroll
    for (int i = 0; i < 4; i++) {
        int f = i * 256 + t;  // float4 index within tile
        int r = f >> 5;       // 32 float4 per row
        int kk = f & 31;
        float4 v;
        int grow = rowbase + r;
        if (grow < N_NODES) {
            v = reinterpret_cast<const float4*>(X + (size_t)grow * K)[kk];
        } else {
            v = make_float4(0.f, 0.f, 0.f, 0.f);
        }
        reinterpret_cast<float4*>(&xs[r][0])[kk] = v;
    }
    __syncthreads();

    int col = t % C_OUT;
    int g = t / C_OUT;  // uniform per wave
    int r0 = g * RPG;

    float acc[RPG];
#pragma unroll
    for (int r = 0; r < RPG; r++) acc[r] = 0.f;

    for (int kk = 0; kk < K / 4; kk++) {
        float w0 = W[(4 * kk + 0) * C_OUT + col];
        float w1 = W[(4 * kk + 1) * C_OUT + col];
        float w2 = W[(4 * kk + 2) * C_OUT + col];
        float w3 = W[(4 * kk + 3) * C_OUT + col];
#pragma unroll
        for (int r = 0; r < RPG; r++) {
            float4 xv = reinterpret_cast<const float4*>(&xs[r0 + r][0])[kk];
            acc[r] = fmaf(xv.x, w0, acc[r]);
            acc[r] = fmaf(xv.y, w1, acc[r]);
            acc[r] = fmaf(xv.z, w2, acc[r]);
            acc[r] = fmaf(xv.w, w3, acc[r]);
        }
    }

#pragma unroll
    for (int r = 0; r < RPG; r++) {
        int grow = rowbase + r0 + r;
        if (grow < N_NODES) H[(size_t)grow * C_OUT + col] = acc[r];
    }
}

// ---------------- aggregation: OUT[n] = dinv[n]*(dinv[n]*H[n] + sum_e dinv[s]*H[s]) + b
template <int C, bool RELU>
__global__ __launch_bounds__(256) void agg_kernel(const float* __restrict__ H,
                                                  const int* __restrict__ off,
                                                  const int* __restrict__ csr_src,
                                                  const float* __restrict__ dinv,
                                                  const float* __restrict__ bias,
                                                  float* __restrict__ OUT) {
    int wave = threadIdx.x >> 6;
    int lane = threadIdx.x & 63;
    int n = blockIdx.x * 4 + wave;
    if (n >= N_NODES) return;

    float dn = dinv[n];
    int e0 = off[n];
    int e1 = off[n + 1];

    if constexpr (C == 128) {
        int c = lane * 2;
        float2 h = reinterpret_cast<const float2*>(H + (size_t)n * C)[lane];
        float2 acc;
        acc.x = dn * h.x;  // self-loop (inner weight dinv[n], outer dn applied later)
        acc.y = dn * h.y;
        for (int e = e0; e < e1; e++) {
            int s = csr_src[e];
            float ds = dinv[s];
            float2 hs = reinterpret_cast<const float2*>(H + (size_t)s * C)[lane];
            acc.x = fmaf(ds, hs.x, acc.x);
            acc.y = fmaf(ds, hs.y, acc.y);
        }
        acc.x = fmaf(acc.x, dn, bias[c]);
        acc.y = fmaf(acc.y, dn, bias[c + 1]);
        if (RELU) {
            acc.x = fmaxf(acc.x, 0.f);
            acc.y = fmaxf(acc.y, 0.f);
        }
        reinterpret_cast<float2*>(OUT + (size_t)n * C)[lane] = acc;
    } else {
        // C == 64: one channel per lane
        float h = H[(size_t)n * C + lane];
        float acc = dn * h;
        for (int e = e0; e < e1; e++) {
            int s = csr_src[e];
            float ds = dinv[s];
            acc = fmaf(ds, H[(size_t)s * C + lane], acc);
        }
        acc = fmaf(acc, dn, bias[lane]);
        if (RELU) acc = fmaxf(acc, 0.f);
        OUT[(size_t)n * C + lane] = acc;
    }
}

// ---------------- launch ----------------
extern "C" void kernel_launch(void* const* d_in, const int* in_sizes, int n_in,
                              void* d_out, int out_size, void* d_ws, size_t ws_size,
                              hipStream_t stream) {
    const float* x  = (const float*)d_in[0];
    const int*   ei = (const int*)d_in[1];
    const float* W1 = (const float*)d_in[2];
    const float* b1 = (const float*)d_in[3];
    const float* W2 = (const float*)d_in[4];
    const float* b2 = (const float*)d_in[5];
    float* out = (float*)d_out;

    char* ws = (char*)d_ws;
    auto alloc = [&](size_t bytes) -> char* {
        char* p = ws;
        ws += (bytes + 255) / 256 * 256;
        return p;
    };
    int* cnt_cur = (int*)alloc((size_t)2 * N_NODES * 4);  // counts | cursor, contiguous
    int* counts = cnt_cur;
    int* cursor = cnt_cur + N_NODES;
    int* off = (int*)alloc((size_t)(N_NODES + 1) * 4);
    int* csr = (int*)alloc((size_t)N_EDGES * 4);
    float* dinv = (float*)alloc((size_t)N_NODES * 4);
    float* h1 = (float*)alloc((size_t)N_NODES * 128 * 4);
    float* g1 = (float*)alloc((size_t)N_NODES * 128 * 4);
    float* h2 = h1;  // layer-1 GEMM output no longer needed after agg1

    zero_int_kernel<<<(2 * N_NODES + 255) / 256, 256, 0, stream>>>(cnt_cur, 2 * N_NODES);
    count_kernel<<<(N_EDGES + 255) / 256, 256, 0, stream>>>(ei, counts);
    scan_kernel<<<1, SCAN_T, 0, stream>>>(counts, off, dinv);
    fill_kernel<<<(N_EDGES + 255) / 256, 256, 0, stream>>>(ei, off, cursor, csr);

    gemm_kernel<128><<<(N_NODES + 31) / 32, 256, 0, stream>>>(x, W1, h1);
    agg_kernel<128, true><<<(N_NODES + 3) / 4, 256, 0, stream>>>(h1, off, csr, dinv, b1, g1);
    gemm_kernel<64><<<(N_NODES + 31) / 32, 256, 0, stream>>>(g1, W2, h2);
    agg_kernel<64, false><<<(N_NODES + 3) / 4, 256, 0, stream>>>(h2, off, csr, dinv, b2, out);
}